// Round 11
// baseline (83.458 us; speedup 1.0000x reference)
//
#include <hip/hip_runtime.h>
#include <math.h>

#define NCLS   80
#define ATTRS  85
#define BATCH  8
#define MAXB   128
#define CHCAP  64   // per-256-chunk positive capacity (mean 0.77, P(>64) ~ 0)
#define POLL_TIMEOUT (1 << 18)

constexpr int G0 = 19, G1 = 38, G2 = 76;
constexpr int S0 = G0 * G0, S1 = G1 * G1, S2 = G2 * G2;          // 361,1444,5776
constexpr int NPOS0 = 3 * S0, NPOS1 = 3 * S1, NPOS2 = 3 * S2;    // 1083,4332,17328
constexpr int NCH0 = (NPOS0 + 255) / 256;                         // 5
constexpr int NCH1 = (NPOS1 + 255) / 256;                         // 17
constexpr int NCH2 = (NPOS2 + 255) / 256;                         // 68
constexpr int CHB1 = NCH0 * BATCH;                                // 40
constexpr int CHB2 = CHB1 + NCH1 * BATCH;                         // 176
constexpr int TOTCH = CHB2 + NCH2 * BATCH;                        // 720
constexpr int BW0 = (NPOS0 + 31) / 32;                            // 34
constexpr int BW1 = (NPOS1 + 31) / 32;                            // 136
constexpr int BW2 = (NPOS2 + 31) / 32;                            // 542
constexpr int BMB0 = 0, BMB1 = BW0 * BATCH, BMB2 = BMB1 + BW1 * BATCH;
// conf geometry: 256 positions per block
constexpr int MC0 = (S0 + 255) / 256, MC1 = (S1 + 255) / 256, MC2 = (S2 + 255) / 256; // 2,6,23
constexpr int MB0 = BATCH * 3 * MC0, MB1 = BATCH * 3 * MC1, MB2 = BATCH * 3 * MC2;    // 48,144,552
constexpr int NMAIN = MB0 + MB1 + MB2;                            // 744
constexpr int NBLK_TOT = TOTCH + NMAIN + 1;                       // 1465 <= 6 blk/CU * 256 CU

// workspace layout (bytes, 16B aligned, NOTHING needs pre-zeroing)
#define OFF_CHUNKCNT 0                         // 720*4 -> pad 4096
#define OFF_CHUNKBOX 4096                      // 720*64*16 = 737280
#define OFF_BITMAP   (4096 + 737280)           // 22784 -> pad 22912
#define OFF_PARTA    (4096 + 737280 + 22912)   // 720*4*4 = 11520
#define OFF_PARTC    (4096 + 737280 + 22912 + 11520) // 744*4

__global__ __launch_bounds__(256, 6) void fused_k(
    const float* __restrict__ yt0, const float* __restrict__ yt1, const float* __restrict__ yt2,
    const float* __restrict__ fm0, const float* __restrict__ fm1, const float* __restrict__ fm2,
    const float* __restrict__ anchors,
    float4* __restrict__ chunkbox, int* __restrict__ chunkcnt,
    unsigned* __restrict__ bitmap,
    float* __restrict__ partA, float* __restrict__ partC,
    float* __restrict__ out)
{
    int blk = blockIdx.x, tid = threadIdx.x, wv = tid >> 6, lane = tid & 63;

    if (blk < TOTCH) {
        // ================= collect block =================
        const float* yt; const float* fm;
        int b, c, npos, s, Sv, G, aoff; float strd;
        if (blk < CHB1)      { int q = blk;        b = q / NCH0; c = q % NCH0; npos = NPOS0; yt = yt0; fm = fm0; s = 0; Sv = S0; G = G0; strd = 32.f; aoff = 12; }
        else if (blk < CHB2) { int q = blk - CHB1; b = q / NCH1; c = q % NCH1; npos = NPOS1; yt = yt1; fm = fm1; s = 1; Sv = S1; G = G1; strd = 16.f; aoff = 6; }
        else                 { int q = blk - CHB2; b = q / NCH2; c = q % NCH2; npos = NPOS2; yt = yt2; fm = fm2; s = 2; Sv = S2; G = G2; strd = 8.f;  aoff = 0; }

        int r = c * 256 + tid;
        bool f = false; size_t off = 0;
        if (r < npos) { off = ((size_t)b * npos + r) * ATTRS; f = (yt[off + 4] > 0.5f); }
        unsigned long long m = __ballot(f);

        __shared__ unsigned long long bal[4];
        __shared__ int pr[CHCAP];
        __shared__ float4 pbox[CHCAP];
        __shared__ float wred[4][3];
        if (lane == 0) bal[wv] = m;
        __syncthreads();

        int nw    = (s == 0) ? BW0 : ((s == 1) ? BW1 : BW2);
        int wbase = ((s == 0) ? BMB0 : ((s == 1) ? BMB1 : BMB2)) + b * nw;
        if (tid < 8) {
            int widx = c * 8 + tid;
            if (widx < nw) {
                unsigned long long bm = bal[tid >> 1];
                bitmap[wbase + widx] = (tid & 1) ? (unsigned)(bm >> 32) : (unsigned)bm;
            }
        }

        int prefix = 0, tot = 0;
        #pragma unroll
        for (int i = 0; i < 4; ++i) { int pc = __popcll(bal[i]); if (i < wv) prefix += pc; tot += pc; }
        int myp = prefix + __popcll(m & ((1ull << lane) - 1ull));

        if (f && myp < CHCAP) {
            float4 v; v.x = yt[off]; v.y = yt[off + 1]; v.z = yt[off + 2]; v.w = yt[off + 3];
            chunkbox[blk * CHCAP + myp] = v;
            pr[myp] = r; pbox[myp] = v;
        }
        __syncthreads();   // all bitmap + chunkbox writes drained (vmcnt 0 before barrier)

        int np = (tot > CHCAP) ? CHCAP : tot;
        if (tid == 0) {
            // RELEASE publish: wbl2 pushes this block's bitmap/box writes to coherence point
            __hip_atomic_store(&chunkcnt[blk], np + 1, __ATOMIC_RELEASE, __HIP_MEMORY_SCOPE_AGENT);
        }

        // positive-only losses (after publication — off the consumer critical path)
        float axy = 0.f, awh = 0.f, acl = 0.f;
        for (int p = wv; p < np; p += 4) {
            int rp = pr[p]; float4 bx = pbox[p];
            int pos = rp / 3, a = rp - pos * 3;
            size_t fb = ((size_t)(b * 255 + a * 85)) * Sv + pos;
            size_t yb = ((size_t)b * npos + rp) * ATTRS;
            float term;
            {
                float pl  = fm[fb + (size_t)(5 + lane) * Sv];
                float tv  = yt[yb + 5 + lane];
                float tgt = 0.99f * tv + 1.25e-4f;
                term = fmaxf(pl, 0.f) - pl * tgt + __logf(1.f + __expf(-fabsf(pl)));
            }
            if (lane < 16) {
                int cc = 64 + lane;
                float pl  = fm[fb + (size_t)(5 + cc) * Sv];
                float tv  = yt[yb + 5 + cc];
                float tgt = 0.99f * tv + 1.25e-4f;
                term += fmaxf(pl, 0.f) - pl * tgt + __logf(1.f + __expf(-fabsf(pl)));
            }
            #pragma unroll
            for (int o = 32; o > 0; o >>= 1) term += __shfl_down(term, o);
            if (lane == 0) {
                float tx = fm[fb];
                float ty = fm[fb + (size_t)Sv];
                float tw = fm[fb + 2 * (size_t)Sv];
                float th = fm[fb + 3 * (size_t)Sv];
                int yr = pos / G, xc = pos - yr * G;
                float sx = 1.f / (1.f + __expf(-tx));
                float sy = 1.f / (1.f + __expf(-ty));
                float predx = (sx + (float)xc) - (float)xc;   // replicate ref rounding
                float predy = (sy + (float)yr) - (float)yr;
                float truex = bx.x / strd - (float)xc;
                float truey = bx.y / strd - (float)yr;
                float bs = 2.f - (bx.z / 608.f) * (bx.w / 608.f);
                float dx = predx - truex, dy = predy - truey;
                axy += 5.f * bs * (dx * dx + dy * dy);
                float aw = anchors[aoff + a * 2], ah = anchors[aoff + a * 2 + 1];
                float ttw = __logf(bx.z / aw), tth = __logf(bx.w / ah);
                float dw = tw - ttw, dh = th - tth;
                awh += 5.f * bs * (dw * dw + dh * dh);
                acl += term;
            }
        }
        if (lane == 0) { wred[wv][0] = axy; wred[wv][1] = awh; wred[wv][2] = acl; }
        __syncthreads();
        if (tid == 0) {
            float4* pav = (float4*)partA;
            pav[blk] = make_float4(wred[0][0] + wred[1][0] + wred[2][0] + wred[3][0],
                                   wred[0][1] + wred[1][1] + wred[2][1] + wred[3][1],
                                   wred[0][2] + wred[1][2] + wred[2][2] + wred[3][2], 0.f);
            __hip_atomic_store(&partA[blk * 4 + 3], 1.0f, __ATOMIC_RELEASE, __HIP_MEMORY_SCOPE_AGENT);
        }

    } else if (blk < TOTCH + NMAIN) {
        // ================= conf block =================
        int u = blk - TOTCH;
        int s, q, nchk, G, Sv, aoff; const float* fm; float strd;
        if (u < MB0)            { s = 0; q = u;             nchk = MC0; G = G0; Sv = S0; fm = fm0; strd = 32.f; aoff = 12; }
        else if (u < MB0 + MB1) { s = 1; q = u - MB0;       nchk = MC1; G = G1; Sv = S1; fm = fm1; strd = 16.f; aoff = 6; }
        else                    { s = 2; q = u - MB0 - MB1; nchk = MC2; G = G2; Sv = S2; fm = fm2; strd = 8.f;  aoff = 0; }
        int b = q / (3 * nchk); int rem = q % (3 * nchk); int a = rem / nchk; int c = rem % nchk;

        __shared__ float4 sbox[MAXB];
        __shared__ int    cs[130], ps[130];
        __shared__ int    tot_s;
        __shared__ float  sred[4];

        int pos = c * 256 + tid;
        int vld = (pos < Sv);
        size_t fb = ((size_t)(b * 255 + a * 85)) * Sv + (vld ? pos : 0);
        // issue fm loads early — polling hides under them
        float tx = fm[fb];
        float ty = fm[fb + (size_t)Sv];
        float tw = fm[fb + 2 * (size_t)Sv];
        float th = fm[fb + 3 * (size_t)Sv];
        float tc = fm[fb + 4 * (size_t)Sv];

        int base = (s == 0) ? (b * NCH0) : ((s == 1) ? (CHB1 + b * NCH1) : (CHB2 + b * NCH2));
        int nch  = (s == 0) ? NCH0 : ((s == 1) ? NCH1 : NCH2);
        if (tid < 128) {
            int v1 = 0;
            if (tid < nch) {
                int it = 0;
                do {
                    v1 = __hip_atomic_load(&chunkcnt[base + tid], __ATOMIC_RELAXED, __HIP_MEMORY_SCOPE_AGENT);
                    if (v1 > 0) break;
                    __builtin_amdgcn_s_sleep(2);
                } while (++it < POLL_TIMEOUT);
            }
            cs[tid] = (v1 > 0) ? (v1 - 1) : 0;
        }
        __syncthreads();
        __threadfence();   // acquire side: invalidate stale cached lines before box/bitmap reads

        if (wv == 0) {
            int c0 = cs[2 * lane], c1 = cs[2 * lane + 1];
            int v = c0 + c1;
            #pragma unroll
            for (int o = 1; o < 64; o <<= 1) {
                int t = __shfl_up(v, o);
                if (lane >= o) v += t;
            }
            int excl = v - (c0 + c1);
            ps[2 * lane]     = excl;
            ps[2 * lane + 1] = excl + c0;
            if (lane == 63) tot_s = v;
        }
        __syncthreads();
        int tot = tot_s;
        int cnt = (tot > MAXB) ? MAXB : tot;

        if (tid < cnt) {
            int lo = 0, hi = nch - 1;
            while (lo < hi) {
                int mid = (lo + hi + 1) >> 1;
                if (ps[mid] <= tid) lo = mid; else hi = mid - 1;
            }
            int j = tid - ps[lo];
            float4 v = chunkbox[(size_t)(base + lo) * CHCAP + j];
            float hw = 0.5f * v.z, hh = 0.5f * v.w;
            sbox[tid] = make_float4(v.x - hw, v.y - hh, v.x + hw, v.y + hh);
        }
        __syncthreads();

        float acc = 0.f;
        if (vld) {
            float aw = anchors[aoff + a * 2], ah = anchors[aoff + a * 2 + 1];
            int yr = pos / G, xc = pos - yr * G;
            float sxg = 1.f / (1.f + __expf(-tx));
            float syg = 1.f / (1.f + __expf(-ty));
            float cx = (sxg + (float)xc) * strd;
            float cy = (syg + (float)yr) * strd;
            float pw = __expf(tw) * aw;
            float ph = __expf(th) * ah;

            int rr = pos * 3 + a;
            int nw    = (s == 0) ? BW0 : ((s == 1) ? BW1 : BW2);
            int wbase = ((s == 0) ? BMB0 : ((s == 1) ? BMB1 : BMB2)) + b * nw;
            unsigned wd = bitmap[wbase + (rr >> 5)];
            float obj = ((wd >> (rr & 31)) & 1u) ? 1.f : 0.f;

            // division-free ignore test: iou > 0.5  <=>  3*inter > pa + ta
            float pa = pw * ph;
            float px0 = cx - 0.5f * pw, py0 = cy - 0.5f * ph;
            float px1 = cx + 0.5f * pw, py1 = cy + 0.5f * ph;
            float best = -1.f;
            for (int j = 0; j < cnt; ++j) {
                float4 bb = sbox[j];
                float ix0 = fmaxf(px0, bb.x);
                float iy0 = fmaxf(py0, bb.y);
                float ix1 = fminf(px1, bb.z);
                float iy1 = fminf(py1, bb.w);
                float iw = fmaxf(ix1 - ix0, 0.f);
                float ih = fmaxf(iy1 - iy0, 0.f);
                float ta = (bb.z - bb.x) * (bb.w - bb.y);
                best = fmaxf(best, 3.f * (iw * ih) - (pa + ta));
            }
            float ign = (best <= 0.f) ? 1.f : 0.f;

            float e    = __expf(-fabsf(tc));
            float l1pe = __logf(1.f + e);
            float bce  = fmaxf(tc, 0.f) - tc * obj + l1pe;
            float sg   = (tc >= 0.f) ? (1.f / (1.f + e)) : (e / (1.f + e));
            float df   = fabsf(obj - sg);
            acc = (obj * bce + 0.5f * (1.f - obj) * ign * bce) * (df * df);
        }

        #pragma unroll
        for (int o = 32; o > 0; o >>= 1) acc += __shfl_down(acc, o);
        if (lane == 0) sred[wv] = acc;
        __syncthreads();
        if (tid == 0) {
            // value IS the ready-flag (>0; poison<0; 0-init=not-ready) — r10-validated
            __hip_atomic_store(&partC[u], sred[0] + sred[1] + sred[2] + sred[3],
                               __ATOMIC_RELAXED, __HIP_MEMORY_SCOPE_AGENT);
        }

    } else {
        // ================= finisher block =================
        // 1) wait for all partA flags
        for (int i = tid; i < TOTCH; i += 256) {
            int it = 0;
            while (it < POLL_TIMEOUT) {
                float v = __hip_atomic_load(&partA[i * 4 + 3], __ATOMIC_RELAXED, __HIP_MEMORY_SCOPE_AGENT);
                if (v == 1.0f) break;
                __builtin_amdgcn_s_sleep(2);
                ++it;
            }
        }
        __syncthreads();
        __threadfence();
        float xy = 0.f, wh = 0.f, cl = 0.f;
        const float4* pav = (const float4*)partA;
        for (int i = tid; i < TOTCH; i += 256) {
            float4 v = pav[i];
            xy += v.x; wh += v.y; cl += v.z;
        }
        // 2) poll conf partials (value-as-flag)
        float cf = 0.f;
        for (int i = tid; i < NMAIN; i += 256) {
            float v; int it = 0;
            do {
                v = __hip_atomic_load(&partC[i], __ATOMIC_RELAXED, __HIP_MEMORY_SCOPE_AGENT);
                if (v > 0.f) break;
                __builtin_amdgcn_s_sleep(2);
            } while (++it < POLL_TIMEOUT);
            cf += (v > 0.f) ? v : 0.f;
        }
        #pragma unroll
        for (int o = 32; o > 0; o >>= 1) {
            xy += __shfl_down(xy, o);
            wh += __shfl_down(wh, o);
            cl += __shfl_down(cl, o);
            cf += __shfl_down(cf, o);
        }
        __shared__ float red[4][4];
        if (lane == 0) { red[wv][0] = xy; red[wv][1] = wh; red[wv][2] = cl; red[wv][3] = cf; }
        __syncthreads();
        if (tid == 0) {
            float X = (red[0][0] + red[1][0] + red[2][0] + red[3][0]) * 0.125f;
            float W = (red[0][1] + red[1][1] + red[2][1] + red[3][1]) * 0.125f;
            float P = (red[0][2] + red[1][2] + red[2][2] + red[3][2]) * 0.125f;
            float C = (red[0][3] + red[1][3] + red[2][3] + red[3][3]) * 0.125f;
            out[0] = X + W + C + P;
            out[1] = X; out[2] = W; out[3] = C; out[4] = P;
        }
    }
}

extern "C" void kernel_launch(void* const* d_in, const int* in_sizes, int n_in,
                              void* d_out, int out_size, void* d_ws, size_t ws_size,
                              hipStream_t stream) {
    const float* fm0 = (const float*)d_in[0];
    const float* yt0 = (const float*)d_in[1];
    const float* fm1 = (const float*)d_in[2];
    const float* yt1 = (const float*)d_in[3];
    const float* fm2 = (const float*)d_in[4];
    const float* yt2 = (const float*)d_in[5];
    const float* anch = (const float*)d_in[6];

    char* ws = (char*)d_ws;
    int*      chunkcnt = (int*)(ws + OFF_CHUNKCNT);
    float4*   chunkbox = (float4*)(ws + OFF_CHUNKBOX);
    unsigned* bitmap   = (unsigned*)(ws + OFF_BITMAP);
    float*    partA    = (float*)(ws + OFF_PARTA);
    float*    partC    = (float*)(ws + OFF_PARTC);

    fused_k<<<NBLK_TOT, 256, 0, stream>>>(yt0, yt1, yt2, fm0, fm1, fm2, anch,
                                          chunkbox, chunkcnt, bitmap,
                                          partA, partC, (float*)d_out);
}

// Round 12
// 31.033 us; speedup vs baseline: 2.6893x; 2.6893x over previous
//
#include <hip/hip_runtime.h>
#include <math.h>

#define NCLS   80
#define ATTRS  85
#define BATCH  8
#define MAXB   128
#define CHCAP  64   // per-256-chunk positive capacity (mean 0.77, P(>64) ~ 0)
#define POLL_TIMEOUT (1 << 18)

constexpr int G0 = 19, G1 = 38, G2 = 76;
constexpr int S0 = G0 * G0, S1 = G1 * G1, S2 = G2 * G2;          // 361,1444,5776
constexpr int NPOS0 = 3 * S0, NPOS1 = 3 * S1, NPOS2 = 3 * S2;    // 1083,4332,17328
constexpr int NCH0 = (NPOS0 + 255) / 256;                         // 5
constexpr int NCH1 = (NPOS1 + 255) / 256;                         // 17
constexpr int NCH2 = (NPOS2 + 255) / 256;                         // 68
constexpr int CHB1 = NCH0 * BATCH;                                // 40
constexpr int CHB2 = CHB1 + NCH1 * BATCH;                         // 176
constexpr int TOTCH = CHB2 + NCH2 * BATCH;                        // 720
constexpr int BW0 = (NPOS0 + 31) / 32;                            // 34
constexpr int BW1 = (NPOS1 + 31) / 32;                            // 136
constexpr int BW2 = (NPOS2 + 31) / 32;                            // 542
constexpr int BMB0 = 0, BMB1 = BW0 * BATCH, BMB2 = BMB1 + BW1 * BATCH;
// conf geometry: 128 positions per block (r9/r10-validated)
#define CPB 128
constexpr int MC0 = (S0 + CPB - 1) / CPB;                         // 3
constexpr int MC1 = (S1 + CPB - 1) / CPB;                         // 12
constexpr int MC2 = (S2 + CPB - 1) / CPB;                         // 46
constexpr int MB0 = BATCH * 3 * MC0, MB1 = BATCH * 3 * MC1, MB2 = BATCH * 3 * MC2;    // 72,288,1104
constexpr int NMAIN = MB0 + MB1 + MB2;                            // 1464
constexpr int NBLK2 = NMAIN + TOTCH + 1;                          // 2185

// workspace layout (bytes, 16B aligned, NOTHING needs pre-zeroing)
#define OFF_CHUNKCNT 0                          // 720*4 -> pad 4096
#define OFF_CHUNKBOX 4096                       // 720*64*16 = 737280
#define OFF_CHUNKIDX (4096 + 737280)            // 720*64*4 = 184320
#define OFF_BITMAP   (4096 + 737280 + 184320)   // 22784 -> pad 22912
#define OFF_PARTA    (4096 + 737280 + 184320 + 22912)  // 720*16 = 11520
#define OFF_PARTC    (4096 + 737280 + 184320 + 22912 + 11520)  // 1464*4

// ====== collectA: PURE obj gather -> bitmap + per-chunk boxes/indices + counts ======
__global__ __launch_bounds__(256) void collectA(
    const float* __restrict__ yt0, const float* __restrict__ yt1, const float* __restrict__ yt2,
    float4* __restrict__ chunkbox, int* __restrict__ chunkidx, int* __restrict__ chunkcnt,
    unsigned* __restrict__ bitmap)
{
    int blk = blockIdx.x;
    const float* yt;
    int b, c, npos, s;
    if (blk < CHB1)      { int q = blk;        b = q / NCH0; c = q % NCH0; npos = NPOS0; yt = yt0; s = 0; }
    else if (blk < CHB2) { int q = blk - CHB1; b = q / NCH1; c = q % NCH1; npos = NPOS1; yt = yt1; s = 1; }
    else                 { int q = blk - CHB2; b = q / NCH2; c = q % NCH2; npos = NPOS2; yt = yt2; s = 2; }

    int tid = threadIdx.x, wv = tid >> 6, lane = tid & 63;
    int r = c * 256 + tid;
    bool f = false; size_t off = 0;
    if (r < npos) { off = ((size_t)b * npos + r) * ATTRS; f = (yt[off + 4] > 0.5f); }
    unsigned long long m = __ballot(f);

    __shared__ unsigned long long bal[4];
    if (lane == 0) bal[wv] = m;
    __syncthreads();

    // obj bitmap: 8 words per chunk, exclusively owned by this block
    int nw    = (s == 0) ? BW0 : ((s == 1) ? BW1 : BW2);
    int wbase = ((s == 0) ? BMB0 : ((s == 1) ? BMB1 : BMB2)) + b * nw;
    if (tid < 8) {
        int widx = c * 8 + tid;
        if (widx < nw) {
            unsigned long long bm = bal[tid >> 1];
            bitmap[wbase + widx] = (tid & 1) ? (unsigned)(bm >> 32) : (unsigned)bm;
        }
    }

    int prefix = 0, tot = 0;
    #pragma unroll
    for (int i = 0; i < 4; ++i) { int pc = __popcll(bal[i]); if (i < wv) prefix += pc; tot += pc; }
    int myp = prefix + __popcll(m & ((1ull << lane) - 1ull));   // block-local rank (index-ordered)

    if (f && myp < CHCAP) {
        float4 v; v.x = yt[off]; v.y = yt[off + 1]; v.z = yt[off + 2]; v.w = yt[off + 3];
        chunkbox[(size_t)blk * CHCAP + myp] = v;
        chunkidx[blk * CHCAP + myp] = r;
    }
    if (tid == 0) chunkcnt[blk] = (tot > CHCAP) ? CHCAP : tot;
}

// ====== work_k: conf blocks [0,NMAIN) + posloss blocks [NMAIN,NMAIN+TOTCH) + finisher ======
__global__ __launch_bounds__(128) void work_k(
    const float* __restrict__ yt0, const float* __restrict__ yt1, const float* __restrict__ yt2,
    const float* __restrict__ fm0, const float* __restrict__ fm1, const float* __restrict__ fm2,
    const float* __restrict__ anchors,
    const float4* __restrict__ chunkbox, const int* __restrict__ chunkidx,
    const int* __restrict__ chunkcnt, const unsigned* __restrict__ bitmap,
    float* __restrict__ partA, float* __restrict__ partC,
    float* __restrict__ out)
{
    int blk = blockIdx.x, tid = threadIdx.x, wv = tid >> 6, lane = tid & 63;

    if (blk < NMAIN) {
        // ================= conf block (r10-validated geometry/math) =================
        int s, q, nchk, G, Sv, aoff; const float* fm; float strd;
        if (blk < MB0)            { s = 0; q = blk;             nchk = MC0; G = G0; Sv = S0; fm = fm0; strd = 32.f; aoff = 12; }
        else if (blk < MB0 + MB1) { s = 1; q = blk - MB0;       nchk = MC1; G = G1; Sv = S1; fm = fm1; strd = 16.f; aoff = 6; }
        else                      { s = 2; q = blk - MB0 - MB1; nchk = MC2; G = G2; Sv = S2; fm = fm2; strd = 8.f;  aoff = 0; }
        int b = q / (3 * nchk); int rem = q % (3 * nchk); int a = rem / nchk; int c = rem % nchk;

        __shared__ float4 sbox[MAXB];
        __shared__ int    cs[130], ps[130];
        __shared__ int    tot_s;
        __shared__ float  sred[2];

        int pos = c * CPB + tid;
        int vld = (pos < Sv);
        size_t fb = ((size_t)(b * 255 + a * 85)) * Sv + (vld ? pos : 0);
        // issue fm loads early — prefix/staging hides under them
        float tx = fm[fb];
        float ty = fm[fb + (size_t)Sv];
        float tw = fm[fb + 2 * (size_t)Sv];
        float th = fm[fb + 3 * (size_t)Sv];
        float tc = fm[fb + 4 * (size_t)Sv];

        int base = (s == 0) ? (b * NCH0) : ((s == 1) ? (CHB1 + b * NCH1) : (CHB2 + b * NCH2));
        int nch  = (s == 0) ? NCH0 : ((s == 1) ? NCH1 : NCH2);
        cs[tid] = (tid < nch) ? chunkcnt[base + tid] : 0;
        __syncthreads();

        if (wv == 0) {
            int c0 = cs[2 * lane], c1 = cs[2 * lane + 1];
            int v = c0 + c1;
            #pragma unroll
            for (int o = 1; o < 64; o <<= 1) {
                int t = __shfl_up(v, o);
                if (lane >= o) v += t;
            }
            int excl = v - (c0 + c1);
            ps[2 * lane]     = excl;
            ps[2 * lane + 1] = excl + c0;
            if (lane == 63) tot_s = v;
        }
        __syncthreads();
        int tot = tot_s;
        int cnt = (tot > MAXB) ? MAXB : tot;

        if (tid < cnt) {
            int lo = 0, hi = nch - 1;
            while (lo < hi) {
                int mid = (lo + hi + 1) >> 1;
                if (ps[mid] <= tid) lo = mid; else hi = mid - 1;
            }
            int j = tid - ps[lo];
            float4 v = chunkbox[(size_t)(base + lo) * CHCAP + j];
            float hw = 0.5f * v.z, hh = 0.5f * v.w;
            sbox[tid] = make_float4(v.x - hw, v.y - hh, v.x + hw, v.y + hh);
        }
        __syncthreads();

        float acc = 0.f;
        if (vld) {
            float aw = anchors[aoff + a * 2], ah = anchors[aoff + a * 2 + 1];
            int yr = pos / G, xc = pos - yr * G;
            float sxg = 1.f / (1.f + __expf(-tx));
            float syg = 1.f / (1.f + __expf(-ty));
            float cx = (sxg + (float)xc) * strd;
            float cy = (syg + (float)yr) * strd;
            float pw = __expf(tw) * aw;
            float ph = __expf(th) * ah;

            int rr = pos * 3 + a;
            int nw    = (s == 0) ? BW0 : ((s == 1) ? BW1 : BW2);
            int wbase = ((s == 0) ? BMB0 : ((s == 1) ? BMB1 : BMB2)) + b * nw;
            unsigned wd = bitmap[wbase + (rr >> 5)];
            float obj = ((wd >> (rr & 31)) & 1u) ? 1.f : 0.f;

            // division-free ignore test: iou > 0.5  <=>  3*inter > pa + ta
            float pa = pw * ph;
            float px0 = cx - 0.5f * pw, py0 = cy - 0.5f * ph;
            float px1 = cx + 0.5f * pw, py1 = cy + 0.5f * ph;
            float best = -1.f;
            for (int j = 0; j < cnt; ++j) {
                float4 bb = sbox[j];
                float ix0 = fmaxf(px0, bb.x);
                float iy0 = fmaxf(py0, bb.y);
                float ix1 = fminf(px1, bb.z);
                float iy1 = fminf(py1, bb.w);
                float iw = fmaxf(ix1 - ix0, 0.f);
                float ih = fmaxf(iy1 - iy0, 0.f);
                float ta = (bb.z - bb.x) * (bb.w - bb.y);
                best = fmaxf(best, 3.f * (iw * ih) - (pa + ta));
            }
            float ign = (best <= 0.f) ? 1.f : 0.f;

            float e    = __expf(-fabsf(tc));
            float l1pe = __logf(1.f + e);
            float bce  = fmaxf(tc, 0.f) - tc * obj + l1pe;
            float sg   = (tc >= 0.f) ? (1.f / (1.f + e)) : (e / (1.f + e));
            float df   = fabsf(obj - sg);
            acc = (obj * bce + 0.5f * (1.f - obj) * ign * bce) * (df * df);
        }

        #pragma unroll
        for (int o = 32; o > 0; o >>= 1) acc += __shfl_down(acc, o);
        if (lane == 0) sred[wv] = acc;
        __syncthreads();
        if (tid == 0) {
            // value IS the ready-flag (>0; poison<0; 0-init=not-ready) — r10-validated
            __hip_atomic_store(&partC[blk], sred[0] + sred[1],
                               __ATOMIC_RELAXED, __HIP_MEMORY_SCOPE_AGENT);
        }

    } else if (blk < NMAIN + TOTCH) {
        // ================= posloss block: one chunk's positive-only losses =================
        int u2 = blk - NMAIN;   // chunk id, 0..719
        const float* yt; const float* fm;
        int b, npos, s, Sv, G, aoff; float strd;
        if (u2 < CHB1)      { int q = u2;        b = q / NCH0; npos = NPOS0; yt = yt0; fm = fm0; s = 0; Sv = S0; G = G0; strd = 32.f; aoff = 12; }
        else if (u2 < CHB2) { int q = u2 - CHB1; b = q / NCH1; npos = NPOS1; yt = yt1; fm = fm1; s = 1; Sv = S1; G = G1; strd = 16.f; aoff = 6; }
        else                { int q = u2 - CHB2; b = q / NCH2; npos = NPOS2; yt = yt2; fm = fm2; s = 2; Sv = S2; G = G2; strd = 8.f;  aoff = 0; }

        __shared__ int    pr[CHCAP];
        __shared__ float4 pbox[CHCAP];
        __shared__ float  wred[2][3];

        int np = chunkcnt[u2];
        if (tid < np) {
            pr[tid]   = chunkidx[u2 * CHCAP + tid];
            pbox[tid] = chunkbox[(size_t)u2 * CHCAP + tid];
        }
        __syncthreads();

        float axy = 0.f, awh = 0.f, acl = 0.f;
        for (int p = wv; p < np; p += 2) {     // one positive per wave, 2 concurrent
            int rp = pr[p]; float4 bx = pbox[p];
            int pos = rp / 3, a = rp - pos * 3;
            size_t fb = ((size_t)(b * 255 + a * 85)) * Sv + pos;
            size_t yb = ((size_t)b * npos + rp) * ATTRS;
            float term;
            {   // class BCE: lanes cover c=lane, plus c=64+lane for lane<16
                float pl  = fm[fb + (size_t)(5 + lane) * Sv];
                float tv  = yt[yb + 5 + lane];
                float tgt = 0.99f * tv + 1.25e-4f;
                term = fmaxf(pl, 0.f) - pl * tgt + __logf(1.f + __expf(-fabsf(pl)));
            }
            if (lane < 16) {
                int cc = 64 + lane;
                float pl  = fm[fb + (size_t)(5 + cc) * Sv];
                float tv  = yt[yb + 5 + cc];
                float tgt = 0.99f * tv + 1.25e-4f;
                term += fmaxf(pl, 0.f) - pl * tgt + __logf(1.f + __expf(-fabsf(pl)));
            }
            #pragma unroll
            for (int o = 32; o > 0; o >>= 1) term += __shfl_down(term, o);
            if (lane == 0) {
                float tx = fm[fb];
                float ty = fm[fb + (size_t)Sv];
                float tw = fm[fb + 2 * (size_t)Sv];
                float th = fm[fb + 3 * (size_t)Sv];
                int yr = pos / G, xc = pos - yr * G;
                float sx = 1.f / (1.f + __expf(-tx));
                float sy = 1.f / (1.f + __expf(-ty));
                float predx = (sx + (float)xc) - (float)xc;   // replicate ref rounding (pow2 stride exact)
                float predy = (sy + (float)yr) - (float)yr;
                float truex = bx.x / strd - (float)xc;
                float truey = bx.y / strd - (float)yr;
                float bs = 2.f - (bx.z / 608.f) * (bx.w / 608.f);
                float dx = predx - truex, dy = predy - truey;
                axy += 5.f * bs * (dx * dx + dy * dy);
                float aw = anchors[aoff + a * 2], ah = anchors[aoff + a * 2 + 1];
                float ttw = __logf(bx.z / aw), tth = __logf(bx.w / ah);   // wh in [10,300]: log safe
                float dw = tw - ttw, dh = th - tth;                        // pred log == tw (validated)
                awh += 5.f * bs * (dw * dw + dh * dh);
                acl += term;
            }
        }
        if (lane == 0) { wred[wv][0] = axy; wred[wv][1] = awh; wred[wv][2] = acl; }
        __syncthreads();
        if (tid == 0) {
            float4* pav = (float4*)partA;
            pav[u2] = make_float4(wred[0][0] + wred[1][0],
                                  wred[0][1] + wred[1][1],
                                  wred[0][2] + wred[1][2], 0.f);
            // release flag AFTER data (poison 0xAA != 1.0f; replay idempotent)
            __hip_atomic_store(&partA[u2 * 4 + 3], 1.0f, __ATOMIC_RELEASE, __HIP_MEMORY_SCOPE_AGENT);
        }

    } else {
        // ================= finisher block =================
        for (int i = tid; i < TOTCH; i += 128) {
            int it = 0;
            while (it < POLL_TIMEOUT) {
                float v = __hip_atomic_load(&partA[i * 4 + 3], __ATOMIC_RELAXED, __HIP_MEMORY_SCOPE_AGENT);
                if (v == 1.0f) break;
                __builtin_amdgcn_s_sleep(2);
                ++it;
            }
        }
        __syncthreads();
        __threadfence();
        float xy = 0.f, wh = 0.f, cl = 0.f;
        const float4* pav = (const float4*)partA;
        for (int i = tid; i < TOTCH; i += 128) {
            float4 v = pav[i];
            xy += v.x; wh += v.y; cl += v.z;
        }
        float cf = 0.f;
        for (int i = tid; i < NMAIN; i += 128) {
            float v; int it = 0;
            do {
                v = __hip_atomic_load(&partC[i], __ATOMIC_RELAXED, __HIP_MEMORY_SCOPE_AGENT);
                if (v > 0.f) break;
                __builtin_amdgcn_s_sleep(2);
            } while (++it < POLL_TIMEOUT);
            cf += (v > 0.f) ? v : 0.f;
        }
        #pragma unroll
        for (int o = 32; o > 0; o >>= 1) {
            xy += __shfl_down(xy, o);
            wh += __shfl_down(wh, o);
            cl += __shfl_down(cl, o);
            cf += __shfl_down(cf, o);
        }
        __shared__ float red[2][4];
        if (lane == 0) { red[wv][0] = xy; red[wv][1] = wh; red[wv][2] = cl; red[wv][3] = cf; }
        __syncthreads();
        if (tid == 0) {
            float X = (red[0][0] + red[1][0]) * 0.125f;
            float W = (red[0][1] + red[1][1]) * 0.125f;
            float P = (red[0][2] + red[1][2]) * 0.125f;
            float C = (red[0][3] + red[1][3]) * 0.125f;
            out[0] = X + W + C + P;
            out[1] = X; out[2] = W; out[3] = C; out[4] = P;
        }
    }
}

extern "C" void kernel_launch(void* const* d_in, const int* in_sizes, int n_in,
                              void* d_out, int out_size, void* d_ws, size_t ws_size,
                              hipStream_t stream) {
    const float* fm0 = (const float*)d_in[0];
    const float* yt0 = (const float*)d_in[1];
    const float* fm1 = (const float*)d_in[2];
    const float* yt1 = (const float*)d_in[3];
    const float* fm2 = (const float*)d_in[4];
    const float* yt2 = (const float*)d_in[5];
    const float* anch = (const float*)d_in[6];

    char* ws = (char*)d_ws;
    int*      chunkcnt = (int*)(ws + OFF_CHUNKCNT);
    float4*   chunkbox = (float4*)(ws + OFF_CHUNKBOX);
    int*      chunkidx = (int*)(ws + OFF_CHUNKIDX);
    unsigned* bitmap   = (unsigned*)(ws + OFF_BITMAP);
    float*    partA    = (float*)(ws + OFF_PARTA);
    float*    partC    = (float*)(ws + OFF_PARTC);

    collectA<<<TOTCH, 256, 0, stream>>>(yt0, yt1, yt2, chunkbox, chunkidx, chunkcnt, bitmap);
    work_k<<<NBLK2, 128, 0, stream>>>(yt0, yt1, yt2, fm0, fm1, fm2, anch,
                                      chunkbox, chunkidx, chunkcnt, bitmap,
                                      partA, partC, (float*)d_out);
}

// Round 13
// 23.257 us; speedup vs baseline: 3.5885x; 1.3343x over previous
//
#include <hip/hip_runtime.h>
#include <math.h>

#define NCLS   80
#define ATTRS  85
#define BATCH  8
#define MAXB   128
#define CHCAP  64   // per-256-chunk positive capacity (mean 0.77, P(>64) ~ 0)
#define POLL_TIMEOUT (1 << 18)

constexpr int G0 = 19, G1 = 38, G2 = 76;
constexpr int S0 = G0 * G0, S1 = G1 * G1, S2 = G2 * G2;          // 361,1444,5776
constexpr int NPOS0 = 3 * S0, NPOS1 = 3 * S1, NPOS2 = 3 * S2;    // 1083,4332,17328
constexpr int NCH0 = (NPOS0 + 255) / 256;                         // 5
constexpr int NCH1 = (NPOS1 + 255) / 256;                         // 17
constexpr int NCH2 = (NPOS2 + 255) / 256;                         // 68
constexpr int CHB1 = NCH0 * BATCH;                                // 40
constexpr int CHB2 = CHB1 + NCH1 * BATCH;                         // 176
constexpr int TOTCH = CHB2 + NCH2 * BATCH;                        // 720
constexpr int BW0 = (NPOS0 + 31) / 32;                            // 34
constexpr int BW1 = (NPOS1 + 31) / 32;                            // 136
constexpr int BW2 = (NPOS2 + 31) / 32;                            // 542
constexpr int BMB0 = 0, BMB1 = BW0 * BATCH, BMB2 = BMB1 + BW1 * BATCH;
// conf geometry: 128 positions per block (r9/r10-validated)
#define CPB 128
constexpr int MC0 = (S0 + CPB - 1) / CPB;                         // 3
constexpr int MC1 = (S1 + CPB - 1) / CPB;                         // 12
constexpr int MC2 = (S2 + CPB - 1) / CPB;                         // 46
constexpr int MB0 = BATCH * 3 * MC0, MB1 = BATCH * 3 * MC1, MB2 = BATCH * 3 * MC2;    // 72,288,1104
constexpr int NMAIN = MB0 + MB1 + MB2;                            // 1464
constexpr int SLOTS_PER_THR = (NMAIN + 127) / 128;                // 12

// workspace layout (bytes, 16B aligned, NOTHING needs pre-zeroing)
#define OFF_CHUNKCNT 0                         // 720*4 -> pad 4096
#define OFF_CHUNKBOX 4096                      // 720*64*16 = 737280
#define OFF_BITMAP   (4096 + 737280)           // 22784 -> pad 22912
#define OFF_PARTA    (4096 + 737280 + 22912)   // 720*16 = 11520
#define OFF_PARTC    (4096 + 737280 + 22912 + 11520) // 1464*4

// ====== collectA: obj gather -> bitmap + per-chunk boxes + positive-only losses ======
__global__ __launch_bounds__(256) void collectA(
    const float* __restrict__ yt0, const float* __restrict__ yt1, const float* __restrict__ yt2,
    const float* __restrict__ fm0, const float* __restrict__ fm1, const float* __restrict__ fm2,
    const float* __restrict__ anchors,
    float4* __restrict__ chunkbox, int* __restrict__ chunkcnt,
    unsigned* __restrict__ bitmap, float* __restrict__ partA)
{
    int blk = blockIdx.x;
    const float* yt; const float* fm;
    int b, c, npos, s, Sv, G, aoff; float strd;
    if (blk < CHB1)      { int q = blk;        b = q / NCH0; c = q % NCH0; npos = NPOS0; yt = yt0; fm = fm0; s = 0; Sv = S0; G = G0; strd = 32.f; aoff = 12; }
    else if (blk < CHB2) { int q = blk - CHB1; b = q / NCH1; c = q % NCH1; npos = NPOS1; yt = yt1; fm = fm1; s = 1; Sv = S1; G = G1; strd = 16.f; aoff = 6; }
    else                 { int q = blk - CHB2; b = q / NCH2; c = q % NCH2; npos = NPOS2; yt = yt2; fm = fm2; s = 2; Sv = S2; G = G2; strd = 8.f;  aoff = 0; }

    int tid = threadIdx.x, wv = tid >> 6, lane = tid & 63;
    int r = c * 256 + tid;
    bool f = false; size_t off = 0;
    if (r < npos) { off = ((size_t)b * npos + r) * ATTRS; f = (yt[off + 4] > 0.5f); }
    unsigned long long m = __ballot(f);

    __shared__ unsigned long long bal[4];
    __shared__ int pr[CHCAP];
    __shared__ float4 pbox[CHCAP];
    __shared__ float wred[4][3];
    if (lane == 0) bal[wv] = m;
    __syncthreads();

    // obj bitmap: 8 words per chunk, exclusively owned by this block
    int nw    = (s == 0) ? BW0 : ((s == 1) ? BW1 : BW2);
    int wbase = ((s == 0) ? BMB0 : ((s == 1) ? BMB1 : BMB2)) + b * nw;
    if (tid < 8) {
        int widx = c * 8 + tid;
        if (widx < nw) {
            unsigned long long bm = bal[tid >> 1];
            bitmap[wbase + widx] = (tid & 1) ? (unsigned)(bm >> 32) : (unsigned)bm;
        }
    }

    int prefix = 0, tot = 0;
    #pragma unroll
    for (int i = 0; i < 4; ++i) { int pc = __popcll(bal[i]); if (i < wv) prefix += pc; tot += pc; }
    int myp = prefix + __popcll(m & ((1ull << lane) - 1ull));   // block-local rank (index-ordered)

    if (f && myp < CHCAP) {
        float4 v; v.x = yt[off]; v.y = yt[off + 1]; v.z = yt[off + 2]; v.w = yt[off + 3];
        chunkbox[(size_t)blk * CHCAP + myp] = v;
        pr[myp] = r; pbox[myp] = v;
    }
    if (tid == 0) chunkcnt[blk] = (tot > CHCAP) ? CHCAP : tot;
    __syncthreads();

    // positive-only losses (ref sums over ALL positives; MAXB caps only the ignore list)
    int np = (tot > CHCAP) ? CHCAP : tot;
    float axy = 0.f, awh = 0.f, acl = 0.f;
    for (int p = wv; p < np; p += 4) {           // one positive per wave, 4 concurrent
        int rp = pr[p]; float4 bx = pbox[p];
        int pos = rp / 3, a = rp - pos * 3;
        size_t fb = ((size_t)(b * 255 + a * 85)) * Sv + pos;
        size_t yb = ((size_t)b * npos + rp) * ATTRS;
        float term;
        {   // class BCE: lanes cover c=lane, plus c=64+lane for lane<16
            float pl  = fm[fb + (size_t)(5 + lane) * Sv];
            float tv  = yt[yb + 5 + lane];
            float tgt = 0.99f * tv + 1.25e-4f;
            term = fmaxf(pl, 0.f) - pl * tgt + __logf(1.f + __expf(-fabsf(pl)));
        }
        if (lane < 16) {
            int cc = 64 + lane;
            float pl  = fm[fb + (size_t)(5 + cc) * Sv];
            float tv  = yt[yb + 5 + cc];
            float tgt = 0.99f * tv + 1.25e-4f;
            term += fmaxf(pl, 0.f) - pl * tgt + __logf(1.f + __expf(-fabsf(pl)));
        }
        #pragma unroll
        for (int o = 32; o > 0; o >>= 1) term += __shfl_down(term, o);
        if (lane == 0) {
            float tx = fm[fb];
            float ty = fm[fb + (size_t)Sv];
            float tw = fm[fb + 2 * (size_t)Sv];
            float th = fm[fb + 3 * (size_t)Sv];
            int yr = pos / G, xc = pos - yr * G;
            float sx = 1.f / (1.f + __expf(-tx));
            float sy = 1.f / (1.f + __expf(-ty));
            float predx = (sx + (float)xc) - (float)xc;   // replicate ref rounding (pow2 stride exact)
            float predy = (sy + (float)yr) - (float)yr;
            float truex = bx.x / strd - (float)xc;
            float truey = bx.y / strd - (float)yr;
            float bs = 2.f - (bx.z / 608.f) * (bx.w / 608.f);
            float dx = predx - truex, dy = predy - truey;
            axy += 5.f * bs * (dx * dx + dy * dy);
            float aw = anchors[aoff + a * 2], ah = anchors[aoff + a * 2 + 1];
            float ttw = __logf(bx.z / aw), tth = __logf(bx.w / ah);   // wh in [10,300]: log safe
            float dw = tw - ttw, dh = th - tth;                        // pred log == tw (validated)
            awh += 5.f * bs * (dw * dw + dh * dh);
            acl += term;
        }
    }
    if (lane == 0) { wred[wv][0] = axy; wred[wv][1] = awh; wred[wv][2] = acl; }
    __syncthreads();
    if (tid == 0) {
        float4* pav = (float4*)partA;
        pav[blk] = make_float4(wred[0][0] + wred[1][0] + wred[2][0] + wred[3][0],
                               wred[0][1] + wred[1][1] + wred[2][1] + wred[3][1],
                               wred[0][2] + wred[1][2] + wred[2][2] + wred[3][2], 0.f);
        // no flag needed: graph edge to node 2 guarantees completion + visibility
    }
}

// ====== conf_final_k: conf blocks + one finisher block (value-as-flag poll, no fences) ======
__global__ __launch_bounds__(128) void conf_final_k(
    const float* __restrict__ fm0, const float* __restrict__ fm1, const float* __restrict__ fm2,
    const float* __restrict__ anchors,
    const float4* __restrict__ chunkbox, const int* __restrict__ chunkcnt,
    const unsigned* __restrict__ bitmap,
    const float4* __restrict__ partA, float* __restrict__ partC,
    float* __restrict__ out)
{
    int blk = blockIdx.x, tid = threadIdx.x;
    int wv = tid >> 6, lane = tid & 63;

    if (blk < NMAIN) {
        // ---------------- conf block (r10-validated geometry/math) ----------------
        int s, q, nchk, G, Sv, aoff; const float* fm; float strd;
        if (blk < MB0)            { s = 0; q = blk;             nchk = MC0; G = G0; Sv = S0; fm = fm0; strd = 32.f; aoff = 12; }
        else if (blk < MB0 + MB1) { s = 1; q = blk - MB0;       nchk = MC1; G = G1; Sv = S1; fm = fm1; strd = 16.f; aoff = 6; }
        else                      { s = 2; q = blk - MB0 - MB1; nchk = MC2; G = G2; Sv = S2; fm = fm2; strd = 8.f;  aoff = 0; }
        int b = q / (3 * nchk); int rem = q % (3 * nchk); int a = rem / nchk; int c = rem % nchk;

        __shared__ float4 sbox[MAXB];
        __shared__ int    cs[130], ps[130];
        __shared__ int    tot_s;
        __shared__ float  sred[2];

        int pos = c * CPB + tid;
        int vld = (pos < Sv);
        size_t fb = ((size_t)(b * 255 + a * 85)) * Sv + (vld ? pos : 0);
        // issue fm loads early — prefix/staging hides under them
        float tx = fm[fb];
        float ty = fm[fb + (size_t)Sv];
        float tw = fm[fb + 2 * (size_t)Sv];
        float th = fm[fb + 3 * (size_t)Sv];
        float tc = fm[fb + 4 * (size_t)Sv];

        int base = (s == 0) ? (b * NCH0) : ((s == 1) ? (CHB1 + b * NCH1) : (CHB2 + b * NCH2));
        int nch  = (s == 0) ? NCH0 : ((s == 1) ? NCH1 : NCH2);
        cs[tid] = (tid < nch) ? chunkcnt[base + tid] : 0;
        __syncthreads();

        if (wv == 0) {
            int c0 = cs[2 * lane], c1 = cs[2 * lane + 1];
            int v = c0 + c1;
            #pragma unroll
            for (int o = 1; o < 64; o <<= 1) {
                int t = __shfl_up(v, o);
                if (lane >= o) v += t;
            }
            int excl = v - (c0 + c1);
            ps[2 * lane]     = excl;
            ps[2 * lane + 1] = excl + c0;
            if (lane == 63) tot_s = v;
        }
        __syncthreads();
        int tot = tot_s;
        int cnt = (tot > MAXB) ? MAXB : tot;

        if (tid < cnt) {
            int lo = 0, hi = nch - 1;
            while (lo < hi) {
                int mid = (lo + hi + 1) >> 1;
                if (ps[mid] <= tid) lo = mid; else hi = mid - 1;
            }
            int j = tid - ps[lo];
            float4 v = chunkbox[(size_t)(base + lo) * CHCAP + j];
            float hw = 0.5f * v.z, hh = 0.5f * v.w;
            sbox[tid] = make_float4(v.x - hw, v.y - hh, v.x + hw, v.y + hh);
        }
        __syncthreads();

        float acc = 0.f;
        if (vld) {
            float aw = anchors[aoff + a * 2], ah = anchors[aoff + a * 2 + 1];
            int yr = pos / G, xc = pos - yr * G;
            float sxg = 1.f / (1.f + __expf(-tx));
            float syg = 1.f / (1.f + __expf(-ty));
            float cx = (sxg + (float)xc) * strd;
            float cy = (syg + (float)yr) * strd;
            float pw = __expf(tw) * aw;
            float ph = __expf(th) * ah;

            int rr = pos * 3 + a;
            int nw    = (s == 0) ? BW0 : ((s == 1) ? BW1 : BW2);
            int wbase = ((s == 0) ? BMB0 : ((s == 1) ? BMB1 : BMB2)) + b * nw;
            unsigned wd = bitmap[wbase + (rr >> 5)];
            float obj = ((wd >> (rr & 31)) & 1u) ? 1.f : 0.f;

            // division-free ignore test: iou > 0.5  <=>  3*inter > pa + ta
            float pa = pw * ph;
            float px0 = cx - 0.5f * pw, py0 = cy - 0.5f * ph;
            float px1 = cx + 0.5f * pw, py1 = cy + 0.5f * ph;
            float best = -1.f;
            for (int j = 0; j < cnt; ++j) {
                float4 bb = sbox[j];
                float ix0 = fmaxf(px0, bb.x);
                float iy0 = fmaxf(py0, bb.y);
                float ix1 = fminf(px1, bb.z);
                float iy1 = fminf(py1, bb.w);
                float iw = fmaxf(ix1 - ix0, 0.f);
                float ih = fmaxf(iy1 - iy0, 0.f);
                float ta = (bb.z - bb.x) * (bb.w - bb.y);
                best = fmaxf(best, 3.f * (iw * ih) - (pa + ta));
            }
            float ign = (best <= 0.f) ? 1.f : 0.f;

            float e    = __expf(-fabsf(tc));
            float l1pe = __logf(1.f + e);
            float bce  = fmaxf(tc, 0.f) - tc * obj + l1pe;
            float sg   = (tc >= 0.f) ? (1.f / (1.f + e)) : (e / (1.f + e));
            float df   = fabsf(obj - sg);
            acc = (obj * bce + 0.5f * (1.f - obj) * ign * bce) * (df * df);
        }

        #pragma unroll
        for (int o = 32; o > 0; o >>= 1) acc += __shfl_down(acc, o);
        if (lane == 0) sred[wv] = acc;
        __syncthreads();
        if (tid == 0) {
            // device-scope relaxed store: value IS the ready-flag (>0; poison<0; 0-init=not-ready)
            __hip_atomic_store(&partC[blk], sred[0] + sred[1],
                               __ATOMIC_RELAXED, __HIP_MEMORY_SCOPE_AGENT);
        }
    } else {
        // ---------------- finisher block ----------------
        // partA is from node 1: graph edge guarantees readiness — plain loads, no polling
        float xy = 0.f, wh = 0.f, cl = 0.f;
        for (int i = tid; i < TOTCH; i += 128) {
            float4 v = partA[i];
            xy += v.x; wh += v.y; cl += v.z;
        }
        // partC: batch-issue all slot loads independently (one latency), re-poll stragglers
        float vv[SLOTS_PER_THR];
        #pragma unroll
        for (int k = 0; k < SLOTS_PER_THR; ++k) {
            int i = tid + k * 128;
            int ic = (i < NMAIN) ? i : 0;
            vv[k] = __hip_atomic_load(&partC[ic], __ATOMIC_RELAXED, __HIP_MEMORY_SCOPE_AGENT);
        }
        float cf = 0.f;
        #pragma unroll
        for (int k = 0; k < SLOTS_PER_THR; ++k) {
            int i = tid + k * 128;
            if (i < NMAIN) {
                float v = vv[k];
                int it = 0;
                while (v <= 0.f && it < POLL_TIMEOUT) {
                    __builtin_amdgcn_s_sleep(2);
                    v = __hip_atomic_load(&partC[i], __ATOMIC_RELAXED, __HIP_MEMORY_SCOPE_AGENT);
                    ++it;
                }
                cf += (v > 0.f) ? v : 0.f;
            }
        }
        #pragma unroll
        for (int o = 32; o > 0; o >>= 1) {
            xy += __shfl_down(xy, o);
            wh += __shfl_down(wh, o);
            cl += __shfl_down(cl, o);
            cf += __shfl_down(cf, o);
        }
        __shared__ float red[2][4];
        if (lane == 0) { red[wv][0] = xy; red[wv][1] = wh; red[wv][2] = cl; red[wv][3] = cf; }
        __syncthreads();
        if (tid == 0) {
            float X = (red[0][0] + red[1][0]) * 0.125f;
            float W = (red[0][1] + red[1][1]) * 0.125f;
            float P = (red[0][2] + red[1][2]) * 0.125f;
            float C = (red[0][3] + red[1][3]) * 0.125f;
            out[0] = X + W + C + P;
            out[1] = X; out[2] = W; out[3] = C; out[4] = P;
        }
    }
}

extern "C" void kernel_launch(void* const* d_in, const int* in_sizes, int n_in,
                              void* d_out, int out_size, void* d_ws, size_t ws_size,
                              hipStream_t stream) {
    const float* fm0 = (const float*)d_in[0];
    const float* yt0 = (const float*)d_in[1];
    const float* fm1 = (const float*)d_in[2];
    const float* yt1 = (const float*)d_in[3];
    const float* fm2 = (const float*)d_in[4];
    const float* yt2 = (const float*)d_in[5];
    const float* anch = (const float*)d_in[6];

    char* ws = (char*)d_ws;
    int*      chunkcnt = (int*)(ws + OFF_CHUNKCNT);
    float4*   chunkbox = (float4*)(ws + OFF_CHUNKBOX);
    unsigned* bitmap   = (unsigned*)(ws + OFF_BITMAP);
    float*    partA    = (float*)(ws + OFF_PARTA);
    float*    partC    = (float*)(ws + OFF_PARTC);

    collectA<<<TOTCH, 256, 0, stream>>>(yt0, yt1, yt2, fm0, fm1, fm2, anch,
                                        chunkbox, chunkcnt, bitmap, partA);
    conf_final_k<<<NMAIN + 1, 128, 0, stream>>>(fm0, fm1, fm2, anch,
                                                chunkbox, chunkcnt, bitmap,
                                                (const float4*)partA, partC, (float*)d_out);
}